// Round 1
// baseline (610.546 us; speedup 1.0000x reference)
//
#include <hip/hip_runtime.h>
#include <math.h>

#define CH 64
#define S 64
#define S2 (64 * 64)
#define S3 (64 * 64 * 64)

// ---------------------------------------------------------------------------
// Kernel 1: Y[b,o,q] = sum_c W[o,c] * V[b,c,q]   (pointwise conv, bias added
// later in the main kernel). Y lives in d_ws (2*64*262144 floats = 128 MB).
// ---------------------------------------------------------------------------
__global__ __launch_bounds__(256) void yconv(const float* __restrict__ V,
                                             const float* __restrict__ W,
                                             float* __restrict__ Y) {
  int idx = blockIdx.x * 256 + threadIdx.x;  // [0, 524288)
  int b = idx >> 18;
  size_t base = ((size_t)b << 24) + (size_t)(idx & (S3 - 1));
  const float* vb = V + base;
  float acc[CH];
#pragma unroll
  for (int o = 0; o < CH; ++o) acc[o] = 0.f;
#pragma unroll 4
  for (int c = 0; c < CH; ++c) {
    float v = vb[(size_t)c << 18];
#pragma unroll
    for (int o = 0; o < CH; ++o) acc[o] = fmaf(W[o * CH + c], v, acc[o]);
  }
  float* yb = Y + base;
#pragma unroll
  for (int o = 0; o < CH; ++o) yb[(size_t)o << 18] = acc[o];
}

// ---------------------------------------------------------------------------
// Halo staging: 4 channels of a (6 z) x (6 y) x (66 x) halo around the
// (4d,4h,64w) tile, zero-filled outside the volume. LDS layout
// [cc:4][z:6][y:6][x:68(pad)], float2 writes (all offsets even -> 8B aligned).
// ---------------------------------------------------------------------------
__device__ __forceinline__ void stage_halo(float* hal, const float* __restrict__ src,
                                           int d0, int h0, int tid) {
  const int NPAIR = 4 * 6 * 6 * 33;  // 4752 float2 elements
#pragma unroll
  for (int it = 0; it < 10; ++it) {
    int f2 = it * 512 + tid;
    if (f2 < NPAIR) {
      int f = f2 * 2;
      int x = f % 66;          // 0..64, even
      int rowi = f / 66;       // 0..143
      int y = rowi % 6;
      int zc = rowi / 6;       // 0..23
      int z = zc % 6;
      int cc = zc / 6;
      int gd = d0 - 1 + z, gh = h0 - 1 + y, gw = x - 1;
      float v0 = 0.f, v1 = 0.f;
      if (((unsigned)gd < 64u) & ((unsigned)gh < 64u)) {
        const float* p = src + ((size_t)cc << 18) + gd * S2 + gh * S + gw;
        if (gw >= 0) v0 = p[0];
        if (gw + 1 < 64) v1 = p[1];
      }
      *(float2*)&hal[((cc * 6 + z) * 6 + y) * 68 + x] = make_float2(v0, v1);
    }
  }
}

// ---------------------------------------------------------------------------
// Kernel 2: fused scores -> softmax -> Y-gather -> out.
// Block: 512 threads = (32 tw) x (4 th) x (4 td); each thread owns 2 adjacent
// w positions (pw = 2*tw, 2*tw+1). Tile = (4 d, 4 h, 64 w) = 1024 positions.
// Grid: 2 (b) * 16 (d0) * 16 (h0) = 512 blocks.
// ---------------------------------------------------------------------------
__global__ __launch_bounds__(512) void attn_main(const float* __restrict__ Q,
                                                 const float* __restrict__ K,
                                                 const float* __restrict__ Y,
                                                 const float* __restrict__ pe,
                                                 const float* __restrict__ bias,
                                                 float* __restrict__ out) {
  __shared__ float hal[4 * 6 * 6 * 68];  // 39168 B
  int tid = threadIdx.x;
  int tw = tid & 31, th = (tid >> 5) & 3, td = tid >> 7;
  int bid = blockIdx.x;
  int b = bid >> 8, r = bid & 255;
  int d0 = (r >> 4) * 4, h0 = (r & 15) * 4;
  size_t bbase = (size_t)b << 24;
  int sp = (d0 + td) * S2 + (h0 + th) * S + 2 * tw;
  int lbase = td * 408 + th * 68 + 2 * tw;  // 408 = 6*68

  float s0[27], s1[27];
#pragma unroll
  for (int t = 0; t < 27; ++t) { s0[t] = 0.f; s1[t] = 0.f; }

  // ---- Phase A: scores over channel chunks of 4 ----
  for (int c0 = 0; c0 < CH; c0 += 4) {
    __syncthreads();  // protect hal from previous chunk's readers
    stage_halo(hal, K + bbase + ((size_t)c0 << 18), d0, h0, tid);
    float2 qv[4];
#pragma unroll
    for (int cc = 0; cc < 4; ++cc)
      qv[cc] = *(const float2*)(Q + bbase + ((size_t)(c0 + cc) << 18) + sp);
    __syncthreads();
#pragma unroll
    for (int cc = 0; cc < 4; ++cc) {
      float q0 = qv[cc].x, q1 = qv[cc].y;
      const float* peb = pe + (c0 + cc) * 27;  // uniform -> scalar loads
#pragma unroll
      for (int dz = 0; dz < 3; ++dz)
#pragma unroll
        for (int dy = 0; dy < 3; ++dy) {
          int la = lbase + cc * 2448 + dz * 408 + dy * 68;
          float2 a = *(const float2*)&hal[la];
          float2 bv = *(const float2*)&hal[la + 2];
          int t = (dz * 3 + dy) * 3;
          s0[t]     = fmaf(q0, a.x,  s0[t]);
          s0[t + 1] = fmaf(q0, a.y,  s0[t + 1]);
          s0[t + 2] = fmaf(q0, bv.x, s0[t + 2]);
          s1[t]     = fmaf(q1, a.y,  s1[t]);
          s1[t + 1] = fmaf(q1, bv.x, s1[t + 1]);
          s1[t + 2] = fmaf(q1, bv.y, s1[t + 2]);
        }
#pragma unroll
      for (int t = 0; t < 27; ++t) {
        float pv = peb[t];
        s0[t] = fmaf(q0, pv, s0[t]);
        s1[t] = fmaf(q1, pv, s1[t]);
      }
    }
  }

  // ---- softmax over the 27 taps (base-2, scale folded; normalize deferred) ----
  const float SC = 0.125f * 1.44269504088896f;  // scale * log2(e)
#pragma unroll
  for (int t = 0; t < 27; ++t) { s0[t] *= SC; s1[t] *= SC; }
  float m0 = s0[0], m1 = s1[0];
#pragma unroll
  for (int t = 1; t < 27; ++t) { m0 = fmaxf(m0, s0[t]); m1 = fmaxf(m1, s1[t]); }
  float sum0 = 0.f, sum1 = 0.f;
#pragma unroll
  for (int t = 0; t < 27; ++t) {
    s0[t] = exp2f(s0[t] - m0); sum0 += s0[t];
    s1[t] = exp2f(s1[t] - m1); sum1 += s1[t];
  }
  float inv0 = 1.f / sum0, inv1 = 1.f / sum1;

  // ---- Phase B: gather Y with attention weights, write out ----
  for (int c0 = 0; c0 < CH; c0 += 4) {
    __syncthreads();
    stage_halo(hal, Y + bbase + ((size_t)c0 << 18), d0, h0, tid);
    __syncthreads();
#pragma unroll
    for (int cc = 0; cc < 4; ++cc) {
      float o0 = 0.f, o1 = 0.f;
#pragma unroll
      for (int dz = 0; dz < 3; ++dz)
#pragma unroll
        for (int dy = 0; dy < 3; ++dy) {
          int la = lbase + cc * 2448 + dz * 408 + dy * 68;
          float2 a = *(const float2*)&hal[la];
          float2 bv = *(const float2*)&hal[la + 2];
          int t = (dz * 3 + dy) * 3;
          o0 = fmaf(s0[t], a.x, o0);
          o0 = fmaf(s0[t + 1], a.y, o0);
          o0 = fmaf(s0[t + 2], bv.x, o0);
          o1 = fmaf(s1[t], a.y, o1);
          o1 = fmaf(s1[t + 1], bv.x, o1);
          o1 = fmaf(s1[t + 2], bv.y, o1);
        }
      float bb = bias[c0 + cc];
      float2 res = make_float2(fmaf(o0, inv0, bb), fmaf(o1, inv1, bb));
      *(float2*)(out + bbase + ((size_t)(c0 + cc) << 18) + sp) = res;
    }
  }
}

// ---------------------------------------------------------------------------
extern "C" void kernel_launch(void* const* d_in, const int* in_sizes, int n_in,
                              void* d_out, int out_size, void* d_ws, size_t ws_size,
                              hipStream_t stream) {
  const float* Q = (const float*)d_in[0];
  const float* K = (const float*)d_in[1];
  const float* V = (const float*)d_in[2];
  const float* pe = (const float*)d_in[3];
  const float* W = (const float*)d_in[4];
  const float* bias = (const float*)d_in[5];
  float* out = (float*)d_out;
  float* Y = (float*)d_ws;  // 2*64*262144 floats = 128 MB scratch

  yconv<<<2048, 256, 0, stream>>>(V, W, Y);
  attn_main<<<512, 512, 0, stream>>>(Q, K, Y, pe, bias, out);
}

// Round 2
// 606.387 us; speedup vs baseline: 1.0069x; 1.0069x over previous
//
#include <hip/hip_runtime.h>
#include <math.h>

#define CH 64
#define S 64
#define S2 (64 * 64)
#define S3 (64 * 64 * 64)

// ---------------------------------------------------------------------------
// Kernel 1: Y[b,o,q] = sum_c W[o,c] * V[b,c,q]. V column cached in 64 VGPRs,
// o-outer so W rows are contiguous -> wide scalar loads (s_load_dwordx16).
// ---------------------------------------------------------------------------
__global__ __launch_bounds__(256, 4) void yconv(const float* __restrict__ V,
                                                const float* __restrict__ W,
                                                float* __restrict__ Y) {
  int idx = blockIdx.x * 256 + threadIdx.x;  // [0, 524288)
  int b = idx >> 18;
  size_t base = ((size_t)b << 24) + (size_t)(idx & (S3 - 1));
  const float* vb = V + base;
  float v[CH];
#pragma unroll
  for (int c = 0; c < CH; ++c) v[c] = vb[(size_t)c << 18];
  float* yb = Y + base;
#pragma unroll 2
  for (int o = 0; o < CH; ++o) {
    const float* wr = W + o * CH;  // uniform, contiguous -> scalar loads
    float acc = 0.f;
#pragma unroll
    for (int c = 0; c < CH; ++c) acc = fmaf(wr[c], v[c], acc);
    yb[(size_t)o << 18] = acc;
  }
}

// ---------------------------------------------------------------------------
// Halo staging for tile (4d, 2h, 64w): 4 channels x (6z)x(4y)x(66x) halo,
// LDS pitch 66. Rows decompose at compile time: 12 passes x 8 rows.
// Interior (x-idx 1..64) written every chunk; edge columns 0/65 are
// permanently zero (written once at kernel start).
// ---------------------------------------------------------------------------
__device__ __forceinline__ void stage_halo(float* hal, const float* __restrict__ src,
                                           int d0, int tid, int gh, bool ghok) {
  int sub = tid & 31;  // float2 index within row
  int hi = (tid >> 7) & 1;
  int y = (tid >> 5) & 3;
#pragma unroll
  for (int p = 0; p < 12; ++p) {
    const int zc0 = 2 * p;
    const int cc = zc0 / 6;       // compile-time (pair never straddles cc)
    const int zb = zc0 - 6 * cc;  // z = zb + hi
    int gd = d0 - 1 + zb + hi;
    bool ok = ghok & ((unsigned)gd < 64u);
    float2 v = make_float2(0.f, 0.f);
    if (ok) v = *(const float2*)(src + ((size_t)cc << 18) + gd * S2 + gh * S + 2 * sub);
    int row = (cc * 6 + zb + hi) * 4 + y;
    int off = row * 66 + 2 * sub + 1;
    hal[off] = v.x;
    hal[off + 1] = v.y;
  }
}

// ---------------------------------------------------------------------------
// Kernel 2: fused scores -> softmax -> Y-gather -> out.
// Block: 256 threads = (32 tw) x (2 th) x (4 td), 2 w-positions per thread.
// Tile (4d, 2h, 64w) = 512 positions. Grid: 2*16*32 = 1024 blocks (4/CU).
// ---------------------------------------------------------------------------
__global__ __launch_bounds__(256, 4) void attn_main(const float* __restrict__ Q,
                                                    const float* __restrict__ K,
                                                    const float* __restrict__ Y,
                                                    const float* __restrict__ pe,
                                                    const float* __restrict__ bias,
                                                    float* __restrict__ out) {
  __shared__ float hal[4 * 6 * 4 * 66];  // 6336 floats = 25344 B
  int tid = threadIdx.x;
  int tw = tid & 31, th = (tid >> 5) & 1, td = tid >> 6;

  // XCD-aware bijective swizzle (1024 % 8 == 0): contiguous 128-block chunks/XCD
  int raw = blockIdx.x;
  int sw = (raw & 7) * 128 + (raw >> 3);
  int b = sw >> 9, r = sw & 511;
  int d0 = (r >> 5) * 4, h0 = (r & 31) * 2;

  size_t bbase = (size_t)b << 24;
  int sp = (d0 + td) * S2 + (h0 + th) * S + 2 * tw;
  int base33 = (td * 4 + th) * 33 + tw;  // float2-index base into halo

  // staging coords (different tid decomposition, fixed per thread)
  int sy = (tid >> 5) & 3;
  int sgh = h0 - 1 + sy;
  bool sghok = (unsigned)sgh < 64u;

  // one-time zero of permanent halo edge columns
  if (tid < 96) hal[tid * 66] = 0.f;
  if (tid >= 128 && tid < 224) hal[(tid - 128) * 66 + 65] = 0.f;

  const float2* h2 = (const float2*)hal;

  float s0[27], s1[27];
#pragma unroll
  for (int t = 0; t < 27; ++t) { s0[t] = 0.f; s1[t] = 0.f; }

  // ---- Phase A: scores over channel chunks of 4 ----
  for (int c0 = 0; c0 < CH; c0 += 4) {
    float2 qv[4];
#pragma unroll
    for (int cc = 0; cc < 4; ++cc)
      qv[cc] = *(const float2*)(Q + bbase + ((size_t)(c0 + cc) << 18) + sp);
    __syncthreads();  // protect hal from previous chunk's readers
    stage_halo(hal, K + bbase + ((size_t)c0 << 18), d0, tid, sgh, sghok);
    __syncthreads();
#pragma unroll
    for (int cc = 0; cc < 4; ++cc) {
      float q0 = qv[cc].x, q1 = qv[cc].y;
      const float* peb = pe + (c0 + cc) * 27;  // uniform -> scalar loads
#pragma unroll
      for (int dz = 0; dz < 3; ++dz)
#pragma unroll
        for (int dy = 0; dy < 3; ++dy) {
          int la = base33 + cc * 792 + dz * 132 + dy * 33;
          float2 a = h2[la];
          float2 bv = h2[la + 1];
          int t = (dz * 3 + dy) * 3;
          s0[t]     = fmaf(q0, a.x,  s0[t]);
          s0[t + 1] = fmaf(q0, a.y,  s0[t + 1]);
          s0[t + 2] = fmaf(q0, bv.x, s0[t + 2]);
          s1[t]     = fmaf(q1, a.y,  s1[t]);
          s1[t + 1] = fmaf(q1, bv.x, s1[t + 1]);
          s1[t + 2] = fmaf(q1, bv.y, s1[t + 2]);
        }
#pragma unroll
      for (int t = 0; t < 27; ++t) {
        float pv = peb[t];
        s0[t] = fmaf(q0, pv, s0[t]);
        s1[t] = fmaf(q1, pv, s1[t]);
      }
    }
  }

  // ---- softmax over 27 taps (base-2; normalization deferred to store) ----
  const float SC = 0.125f * 1.44269504088896f;
#pragma unroll
  for (int t = 0; t < 27; ++t) { s0[t] *= SC; s1[t] *= SC; }
  float m0 = s0[0], m1 = s1[0];
#pragma unroll
  for (int t = 1; t < 27; ++t) { m0 = fmaxf(m0, s0[t]); m1 = fmaxf(m1, s1[t]); }
  float sum0 = 0.f, sum1 = 0.f;
#pragma unroll
  for (int t = 0; t < 27; ++t) {
    s0[t] = exp2f(s0[t] - m0); sum0 += s0[t];
    s1[t] = exp2f(s1[t] - m1); sum1 += s1[t];
  }
  float inv0 = 1.f / sum0, inv1 = 1.f / sum1;

  // ---- Phase B: gather Y with attention weights, write out ----
  for (int c0 = 0; c0 < CH; c0 += 4) {
    __syncthreads();
    stage_halo(hal, Y + bbase + ((size_t)c0 << 18), d0, tid, sgh, sghok);
    __syncthreads();
#pragma unroll
    for (int cc = 0; cc < 4; ++cc) {
      float o0 = 0.f, o1 = 0.f;
#pragma unroll
      for (int dz = 0; dz < 3; ++dz)
#pragma unroll
        for (int dy = 0; dy < 3; ++dy) {
          int la = base33 + cc * 792 + dz * 132 + dy * 33;
          float2 a = h2[la];
          float2 bv = h2[la + 1];
          int t = (dz * 3 + dy) * 3;
          o0 = fmaf(s0[t], a.x, o0);
          o0 = fmaf(s0[t + 1], a.y, o0);
          o0 = fmaf(s0[t + 2], bv.x, o0);
          o1 = fmaf(s1[t], a.y, o1);
          o1 = fmaf(s1[t + 1], bv.x, o1);
          o1 = fmaf(s1[t + 2], bv.y, o1);
        }
      float bb = bias[c0 + cc];
      float2 res = make_float2(fmaf(o0, inv0, bb), fmaf(o1, inv1, bb));
      *(float2*)(out + bbase + ((size_t)(c0 + cc) << 18) + sp) = res;
    }
  }
}

// ---------------------------------------------------------------------------
extern "C" void kernel_launch(void* const* d_in, const int* in_sizes, int n_in,
                              void* d_out, int out_size, void* d_ws, size_t ws_size,
                              hipStream_t stream) {
  const float* Q = (const float*)d_in[0];
  const float* K = (const float*)d_in[1];
  const float* V = (const float*)d_in[2];
  const float* pe = (const float*)d_in[3];
  const float* W = (const float*)d_in[4];
  const float* bias = (const float*)d_in[5];
  float* out = (float*)d_out;
  float* Y = (float*)d_ws;  // 128 MB scratch

  yconv<<<2048, 256, 0, stream>>>(V, W, Y);
  attn_main<<<1024, 256, 0, stream>>>(Q, K, Y, pe, bias, out);
}

// Round 3
// 499.169 us; speedup vs baseline: 1.2231x; 1.2148x over previous
//
#include <hip/hip_runtime.h>
#include <math.h>

#define CH 64
#define S 64
#define S2 (64 * 64)
#define S3 (64 * 64 * 64)

__device__ float WT_buf[CH * CH];  // W transposed: WT[c][o]

// ---------------------------------------------------------------------------
// Kernel 0: transpose W (64x64) into WT_buf. Trivial.
// ---------------------------------------------------------------------------
__global__ __launch_bounds__(256) void wtrans(const float* __restrict__ W) {
  int i = blockIdx.x * 256 + threadIdx.x;  // 4096 threads
  int o = i >> 6, c = i & 63;
  WT_buf[c * CH + o] = W[o * CH + c];
}

// ---------------------------------------------------------------------------
// Kernel 1: Y[b,o,q] = sum_c W[o,c] * V[b,c,q]. acc[64] in VGPRs (full ILP),
// per-c W row contiguous from WT_buf -> wide scalar loads.
// ---------------------------------------------------------------------------
__global__ __launch_bounds__(256) void yconv(const float* __restrict__ V,
                                             float* __restrict__ Y) {
  int idx = blockIdx.x * 256 + threadIdx.x;  // [0, 524288)
  int b = idx >> 18;
  size_t base = ((size_t)b << 24) + (size_t)(idx & (S3 - 1));
  const float* vb = V + base;
  float acc[CH];
#pragma unroll
  for (int o = 0; o < CH; ++o) acc[o] = 0.f;
#pragma unroll 2
  for (int c = 0; c < CH; ++c) {
    float v = vb[(size_t)c << 18];
    const float* wr = WT_buf + c * CH;  // uniform, contiguous -> s_load_dwordx16
#pragma unroll
    for (int o = 0; o < CH; ++o) acc[o] = fmaf(wr[o], v, acc[o]);
  }
  float* yb = Y + base;
#pragma unroll
  for (int o = 0; o < CH; ++o) yb[(size_t)o << 18] = acc[o];
}

// ---------------------------------------------------------------------------
// Halo staging for tile (4d, 2h, 64w): 4 channels x (6z)x(4y)x(66x), pitch 66.
// Split into load (global -> 12 float2 regs, issued EARLY) and write
// (regs -> LDS, after the barrier). Compile-time (cc,zb) decomposition.
// ---------------------------------------------------------------------------
__device__ __forceinline__ void stage_load(const float* __restrict__ src, int d0,
                                           int tid, int gh, bool ghok, float2* v) {
  int sub = tid & 31;
  int hi = (tid >> 7) & 1;
#pragma unroll
  for (int p = 0; p < 12; ++p) {
    const int cc = (2 * p) / 6;
    const int zb = 2 * p - 6 * cc;
    int gd = d0 - 1 + zb + hi;
    bool ok = ghok & ((unsigned)gd < 64u);
    v[p] = make_float2(0.f, 0.f);
    if (ok) v[p] = *(const float2*)(src + ((size_t)cc << 18) + gd * S2 + gh * S + 2 * sub);
  }
}

__device__ __forceinline__ void stage_write(float* hal, int tid, const float2* v) {
  int sub = tid & 31;
  int hi = (tid >> 7) & 1;
  int y = (tid >> 5) & 3;
#pragma unroll
  for (int p = 0; p < 12; ++p) {
    const int cc = (2 * p) / 6;
    const int zb = 2 * p - 6 * cc;
    int row = (cc * 6 + zb + hi) * 4 + y;
    int off = row * 66 + 2 * sub + 1;
    hal[off] = v[p].x;
    hal[off + 1] = v[p].y;
  }
}

__device__ __forceinline__ void qload(const float* __restrict__ Qb, int sp, int c0,
                                      float2* q) {
#pragma unroll
  for (int cc = 0; cc < 4; ++cc)
    q[cc] = *(const float2*)(Qb + ((size_t)(c0 + cc) << 18) + sp);
}

__device__ __forceinline__ void compute_scores(const float2* h2, int base33,
                                               const float2* qv,
                                               const float* __restrict__ peb,
                                               float* s0, float* s1) {
#pragma unroll
  for (int cc = 0; cc < 4; ++cc) {
    float q0 = qv[cc].x, q1 = qv[cc].y;
    const float* pec = peb + cc * 27;  // uniform -> scalar loads
#pragma unroll
    for (int dz = 0; dz < 3; ++dz)
#pragma unroll
      for (int dy = 0; dy < 3; ++dy) {
        int la = base33 + cc * 792 + dz * 132 + dy * 33;
        float2 a = h2[la];
        float2 bv = h2[la + 1];
        int t = (dz * 3 + dy) * 3;
        s0[t]     = fmaf(q0, a.x,  s0[t]);
        s0[t + 1] = fmaf(q0, a.y,  s0[t + 1]);
        s0[t + 2] = fmaf(q0, bv.x, s0[t + 2]);
        s1[t]     = fmaf(q1, a.y,  s1[t]);
        s1[t + 1] = fmaf(q1, bv.x, s1[t + 1]);
        s1[t + 2] = fmaf(q1, bv.y, s1[t + 2]);
      }
#pragma unroll
    for (int t = 0; t < 27; ++t) {
      float pv = pec[t];
      s0[t] = fmaf(q0, pv, s0[t]);
      s1[t] = fmaf(q1, pv, s1[t]);
    }
  }
}

__device__ __forceinline__ void gather_store(const float2* h2, int base33,
                                             const float* s0, const float* s1,
                                             float inv0, float inv1,
                                             const float* __restrict__ bias, int c0,
                                             float* __restrict__ outb, int sp) {
#pragma unroll
  for (int cc = 0; cc < 4; ++cc) {
    float o0 = 0.f, o1 = 0.f;
#pragma unroll
    for (int dz = 0; dz < 3; ++dz)
#pragma unroll
      for (int dy = 0; dy < 3; ++dy) {
        int la = base33 + cc * 792 + dz * 132 + dy * 33;
        float2 a = h2[la];
        float2 bv = h2[la + 1];
        int t = (dz * 3 + dy) * 3;
        o0 = fmaf(s0[t], a.x, o0);
        o0 = fmaf(s0[t + 1], a.y, o0);
        o0 = fmaf(s0[t + 2], bv.x, o0);
        o1 = fmaf(s1[t], a.y, o1);
        o1 = fmaf(s1[t + 1], bv.x, o1);
        o1 = fmaf(s1[t + 2], bv.y, o1);
      }
    float bb = bias[c0 + cc];
    *(float2*)(outb + ((size_t)(c0 + cc) << 18) + sp) =
        make_float2(fmaf(o0, inv0, bb), fmaf(o1, inv1, bb));
  }
}

// ---------------------------------------------------------------------------
// Kernel 2: fused scores -> softmax -> Y-gather -> out, software-pipelined:
// chunk n+1's global loads are issued before chunk n's compute, LDS-written
// after the post-compute barrier. Block 256 = (32 tw)x(2 th)x(4 td),
// tile (4d,2h,64w), grid 1024.
// ---------------------------------------------------------------------------
__global__ __launch_bounds__(256, 4) void attn_main(const float* __restrict__ Q,
                                                    const float* __restrict__ K,
                                                    const float* __restrict__ Y,
                                                    const float* __restrict__ pe,
                                                    const float* __restrict__ bias,
                                                    float* __restrict__ out) {
  __shared__ float hal[96 * 66];  // 25344 B
  int tid = threadIdx.x;
  int tw = tid & 31, th = (tid >> 5) & 1, td = tid >> 6;

  // XCD-aware bijective swizzle (1024 % 8 == 0)
  int raw = blockIdx.x;
  int sw = (raw & 7) * 128 + (raw >> 3);
  int b = sw >> 9, r = sw & 511;
  int d0 = (r >> 5) * 4, h0 = (r & 31) * 2;

  size_t bbase = (size_t)b << 24;
  int sp = (d0 + td) * S2 + (h0 + th) * S + 2 * tw;
  int base33 = (td * 4 + th) * 33 + tw;

  int sy = (tid >> 5) & 3;
  int sgh = h0 - 1 + sy;
  bool sghok = (unsigned)sgh < 64u;

  const float* Qb = Q + bbase;
  const float* Kb = K + bbase;
  const float* Yb = Y + bbase;
  float* outb = out + bbase;

  // one-time zero of permanent halo edge columns (gw=-1 and gw=64)
  if (tid < 96) hal[tid * 66] = 0.f;
  if (tid >= 128 && tid < 224) hal[(tid - 128) * 66 + 65] = 0.f;

  const float2* h2 = (const float2*)hal;

  float2 sreg[12], qn[4];
  // prologue: stage chunk 0 of K, prefetch Q chunk 0
  stage_load(Kb, d0, tid, sgh, sghok, sreg);
  qload(Qb, sp, 0, qn);
  stage_write(hal, tid, sreg);
  __syncthreads();

  float s0[27], s1[27];
#pragma unroll
  for (int t = 0; t < 27; ++t) { s0[t] = 0.f; s1[t] = 0.f; }

  // ---- Phase A: scores ----
  for (int i = 0; i < 15; ++i) {
    float2 qv[4];
#pragma unroll
    for (int cc = 0; cc < 4; ++cc) qv[cc] = qn[cc];
    int c0 = 4 * i;
    stage_load(Kb + ((size_t)(c0 + 4) << 18), d0, tid, sgh, sghok, sreg);
    qload(Qb, sp, c0 + 4, qn);
    compute_scores(h2, base33, qv, pe + c0 * 27, s0, s1);
    __syncthreads();
    stage_write(hal, tid, sreg);  // compiler emits vmcnt wait here
    __syncthreads();
  }
  {  // i = 15: prefetch phase B's first Y chunk
    stage_load(Yb, d0, tid, sgh, sghok, sreg);
    compute_scores(h2, base33, qn, pe + 60 * 27, s0, s1);
    __syncthreads();
    stage_write(hal, tid, sreg);
    __syncthreads();
  }

  // ---- softmax over 27 taps (base-2; normalization deferred) ----
  const float SC = 0.125f * 1.44269504088896f;
#pragma unroll
  for (int t = 0; t < 27; ++t) { s0[t] *= SC; s1[t] *= SC; }
  float m0 = s0[0], m1 = s1[0];
#pragma unroll
  for (int t = 1; t < 27; ++t) { m0 = fmaxf(m0, s0[t]); m1 = fmaxf(m1, s1[t]); }
  float sum0 = 0.f, sum1 = 0.f;
#pragma unroll
  for (int t = 0; t < 27; ++t) {
    s0[t] = exp2f(s0[t] - m0); sum0 += s0[t];
    s1[t] = exp2f(s1[t] - m1); sum1 += s1[t];
  }
  float inv0 = 1.f / sum0, inv1 = 1.f / sum1;

  // ---- Phase B: gather Y, write out ----
  for (int i = 0; i < 15; ++i) {
    int c0 = 4 * i;
    stage_load(Yb + ((size_t)(c0 + 4) << 18), d0, tid, sgh, sghok, sreg);
    gather_store(h2, base33, s0, s1, inv0, inv1, bias, c0, outb, sp);
    __syncthreads();
    stage_write(hal, tid, sreg);
    __syncthreads();
  }
  gather_store(h2, base33, s0, s1, inv0, inv1, bias, 60, outb, sp);
}

// ---------------------------------------------------------------------------
extern "C" void kernel_launch(void* const* d_in, const int* in_sizes, int n_in,
                              void* d_out, int out_size, void* d_ws, size_t ws_size,
                              hipStream_t stream) {
  const float* Q = (const float*)d_in[0];
  const float* K = (const float*)d_in[1];
  const float* V = (const float*)d_in[2];
  const float* pe = (const float*)d_in[3];
  const float* W = (const float*)d_in[4];
  const float* bias = (const float*)d_in[5];
  float* out = (float*)d_out;
  float* Y = (float*)d_ws;  // 128 MB scratch

  wtrans<<<16, 256, 0, stream>>>(W);
  yconv<<<2048, 256, 0, stream>>>(V, Y);
  attn_main<<<1024, 256, 0, stream>>>(Q, K, Y, pe, bias, out);
}

// Round 4
// 367.847 us; speedup vs baseline: 1.6598x; 1.3570x over previous
//
#include <hip/hip_runtime.h>
#include <math.h>

#define CH 64
#define S 64
#define S2 (64 * 64)
#define S3 (64 * 64 * 64)

__device__ float WT_buf[CH * CH];  // W transposed: WT[c][o]

// ---------------------------------------------------------------------------
// Kernel 0: transpose W (64x64) into WT_buf. Trivial.
// ---------------------------------------------------------------------------
__global__ __launch_bounds__(256) void wtrans(const float* __restrict__ W) {
  int i = blockIdx.x * 256 + threadIdx.x;  // 4096 threads
  int o = i >> 6, c = i & 63;
  WT_buf[c * CH + o] = W[o * CH + c];
}

// ---------------------------------------------------------------------------
// Kernel 1: Y[b,o,q] = sum_c W[o,c] * V[b,c,q]. acc[64] in VGPRs (full ILP),
// per-c W row contiguous from WT_buf -> wide scalar loads. At memory roofline.
// ---------------------------------------------------------------------------
__global__ __launch_bounds__(256) void yconv(const float* __restrict__ V,
                                             float* __restrict__ Y) {
  int idx = blockIdx.x * 256 + threadIdx.x;  // [0, 524288)
  int b = idx >> 18;
  size_t base = ((size_t)b << 24) + (size_t)(idx & (S3 - 1));
  const float* vb = V + base;
  float acc[CH];
#pragma unroll
  for (int o = 0; o < CH; ++o) acc[o] = 0.f;
#pragma unroll 2
  for (int c = 0; c < CH; ++c) {
    float v = vb[(size_t)c << 18];
    const float* wr = WT_buf + c * CH;  // uniform, contiguous -> s_load_dwordx16
#pragma unroll
    for (int o = 0; o < CH; ++o) acc[o] = fmaf(wr[o], v, acc[o]);
  }
  float* yb = Y + base;
#pragma unroll
  for (int o = 0; o < CH; ++o) yb[(size_t)o << 18] = acc[o];
}

// ---------------------------------------------------------------------------
// Halo staging for tile (4d, 2h, 64w): 4 channels x (6z)x(4y)x(66x), pitch 66.
// Split into load (global -> 12 float2 regs, issued EARLY) and write
// (regs -> LDS, after the barrier). Compile-time (cc,zb) decomposition.
// ---------------------------------------------------------------------------
__device__ __forceinline__ void stage_load(const float* __restrict__ src, int d0,
                                           int tid, int gh, bool ghok, float2* v) {
  int sub = tid & 31;
  int hi = (tid >> 7) & 1;
#pragma unroll
  for (int p = 0; p < 12; ++p) {
    const int cc = (2 * p) / 6;
    const int zb = 2 * p - 6 * cc;
    int gd = d0 - 1 + zb + hi;
    bool ok = ghok & ((unsigned)gd < 64u);
    v[p] = make_float2(0.f, 0.f);
    if (ok) v[p] = *(const float2*)(src + ((size_t)cc << 18) + gd * S2 + gh * S + 2 * sub);
  }
}

__device__ __forceinline__ void stage_write(float* hal, int tid, const float2* v) {
  int sub = tid & 31;
  int hi = (tid >> 7) & 1;
  int y = (tid >> 5) & 3;
#pragma unroll
  for (int p = 0; p < 12; ++p) {
    const int cc = (2 * p) / 6;
    const int zb = 2 * p - 6 * cc;
    int row = (cc * 6 + zb + hi) * 4 + y;
    int off = row * 66 + 2 * sub + 1;
    hal[off] = v[p].x;
    hal[off + 1] = v[p].y;
  }
}

__device__ __forceinline__ void qload(const float* __restrict__ Qb, int sp, int c0,
                                      float2* q) {
#pragma unroll
  for (int cc = 0; cc < 4; ++cc)
    q[cc] = *(const float2*)(Qb + ((size_t)(c0 + cc) << 18) + sp);
}

__device__ __forceinline__ void compute_scores(const float2* h2, int base33,
                                               const float2* qv,
                                               const float* __restrict__ peb,
                                               float* s0, float* s1) {
#pragma unroll
  for (int cc = 0; cc < 4; ++cc) {
    float q0 = qv[cc].x, q1 = qv[cc].y;
    const float* pec = peb + cc * 27;  // uniform -> scalar loads
#pragma unroll
    for (int dz = 0; dz < 3; ++dz)
#pragma unroll
      for (int dy = 0; dy < 3; ++dy) {
        int la = base33 + cc * 792 + dz * 132 + dy * 33;
        float2 a = h2[la];
        float2 bv = h2[la + 1];
        int t = (dz * 3 + dy) * 3;
        s0[t]     = fmaf(q0, a.x,  s0[t]);
        s0[t + 1] = fmaf(q0, a.y,  s0[t + 1]);
        s0[t + 2] = fmaf(q0, bv.x, s0[t + 2]);
        s1[t]     = fmaf(q1, a.y,  s1[t]);
        s1[t + 1] = fmaf(q1, bv.x, s1[t + 1]);
        s1[t + 2] = fmaf(q1, bv.y, s1[t + 2]);
      }
#pragma unroll
    for (int t = 0; t < 27; ++t) {
      float pv = pec[t];
      s0[t] = fmaf(q0, pv, s0[t]);
      s1[t] = fmaf(q1, pv, s1[t]);
    }
  }
}

__device__ __forceinline__ void gather_store(const float2* h2, int base33,
                                             const float* s0, const float* s1,
                                             float inv0, float inv1,
                                             const float* __restrict__ bias, int c0,
                                             float* __restrict__ outb, int sp) {
#pragma unroll
  for (int cc = 0; cc < 4; ++cc) {
    float o0 = 0.f, o1 = 0.f;
#pragma unroll
    for (int dz = 0; dz < 3; ++dz)
#pragma unroll
      for (int dy = 0; dy < 3; ++dy) {
        int la = base33 + cc * 792 + dz * 132 + dy * 33;
        float2 a = h2[la];
        float2 bv = h2[la + 1];
        int t = (dz * 3 + dy) * 3;
        o0 = fmaf(s0[t], a.x, o0);
        o0 = fmaf(s0[t + 1], a.y, o0);
        o0 = fmaf(s0[t + 2], bv.x, o0);
        o1 = fmaf(s1[t], a.y, o1);
        o1 = fmaf(s1[t + 1], bv.x, o1);
        o1 = fmaf(s1[t + 2], bv.y, o1);
      }
    float bb = bias[c0 + cc];
    *(float2*)(outb + ((size_t)(c0 + cc) << 18) + sp) =
        make_float2(fmaf(o0, inv0, bb), fmaf(o1, inv1, bb));
  }
}

// ---------------------------------------------------------------------------
// Kernel 2: fused scores -> softmax -> Y-gather -> out, software-pipelined.
// NOTE: no waves-per-EU bound — r2/r3's __launch_bounds__(256,4) made the
// allocator pick 64 VGPRs and spill ~470 MB to scratch (WRITE_SIZE 502-604 MB
// vs 134 MB of real output). Live state needs ~110-130 VGPRs.
// ---------------------------------------------------------------------------
__global__ __launch_bounds__(256) void attn_main(const float* __restrict__ Q,
                                                 const float* __restrict__ K,
                                                 const float* __restrict__ Y,
                                                 const float* __restrict__ pe,
                                                 const float* __restrict__ bias,
                                                 float* __restrict__ out) {
  __shared__ float hal[96 * 66];  // 25344 B
  int tid = threadIdx.x;
  int tw = tid & 31, th = (tid >> 5) & 1, td = tid >> 6;

  // XCD-aware bijective swizzle (1024 % 8 == 0)
  int raw = blockIdx.x;
  int sw = (raw & 7) * 128 + (raw >> 3);
  int b = sw >> 9, r = sw & 511;
  int d0 = (r >> 5) * 4, h0 = (r & 31) * 2;

  size_t bbase = (size_t)b << 24;
  int sp = (d0 + td) * S2 + (h0 + th) * S + 2 * tw;
  int base33 = (td * 4 + th) * 33 + tw;

  int sy = (tid >> 5) & 3;
  int sgh = h0 - 1 + sy;
  bool sghok = (unsigned)sgh < 64u;

  const float* Qb = Q + bbase;
  const float* Kb = K + bbase;
  const float* Yb = Y + bbase;
  float* outb = out + bbase;

  // one-time zero of permanent halo edge columns (gw=-1 and gw=64)
  if (tid < 96) hal[tid * 66] = 0.f;
  if (tid >= 128 && tid < 224) hal[(tid - 128) * 66 + 65] = 0.f;

  const float2* h2 = (const float2*)hal;

  float2 sreg[12], qn[4];
  // prologue: stage chunk 0 of K, prefetch Q chunk 0
  stage_load(Kb, d0, tid, sgh, sghok, sreg);
  qload(Qb, sp, 0, qn);
  stage_write(hal, tid, sreg);
  __syncthreads();

  float s0[27], s1[27];
#pragma unroll
  for (int t = 0; t < 27; ++t) { s0[t] = 0.f; s1[t] = 0.f; }

  // ---- Phase A: scores ----
  for (int i = 0; i < 15; ++i) {
    float2 qv[4];
#pragma unroll
    for (int cc = 0; cc < 4; ++cc) qv[cc] = qn[cc];
    int c0 = 4 * i;
    stage_load(Kb + ((size_t)(c0 + 4) << 18), d0, tid, sgh, sghok, sreg);
    qload(Qb, sp, c0 + 4, qn);
    compute_scores(h2, base33, qv, pe + c0 * 27, s0, s1);
    __syncthreads();
    stage_write(hal, tid, sreg);  // compiler emits vmcnt wait here
    __syncthreads();
  }
  {  // i = 15: prefetch phase B's first Y chunk
    stage_load(Yb, d0, tid, sgh, sghok, sreg);
    compute_scores(h2, base33, qn, pe + 60 * 27, s0, s1);
    __syncthreads();
    stage_write(hal, tid, sreg);
    __syncthreads();
  }

  // ---- softmax over 27 taps (base-2; normalization deferred) ----
  const float SC = 0.125f * 1.44269504088896f;
#pragma unroll
  for (int t = 0; t < 27; ++t) { s0[t] *= SC; s1[t] *= SC; }
  float m0 = s0[0], m1 = s1[0];
#pragma unroll
  for (int t = 1; t < 27; ++t) { m0 = fmaxf(m0, s0[t]); m1 = fmaxf(m1, s1[t]); }
  float sum0 = 0.f, sum1 = 0.f;
#pragma unroll
  for (int t = 0; t < 27; ++t) {
    s0[t] = exp2f(s0[t] - m0); sum0 += s0[t];
    s1[t] = exp2f(s1[t] - m1); sum1 += s1[t];
  }
  float inv0 = 1.f / sum0, inv1 = 1.f / sum1;

  // ---- Phase B: gather Y, write out ----
  for (int i = 0; i < 15; ++i) {
    int c0 = 4 * i;
    stage_load(Yb + ((size_t)(c0 + 4) << 18), d0, tid, sgh, sghok, sreg);
    gather_store(h2, base33, s0, s1, inv0, inv1, bias, c0, outb, sp);
    __syncthreads();
    stage_write(hal, tid, sreg);
    __syncthreads();
  }
  gather_store(h2, base33, s0, s1, inv0, inv1, bias, 60, outb, sp);
}

// ---------------------------------------------------------------------------
extern "C" void kernel_launch(void* const* d_in, const int* in_sizes, int n_in,
                              void* d_out, int out_size, void* d_ws, size_t ws_size,
                              hipStream_t stream) {
  const float* Q = (const float*)d_in[0];
  const float* K = (const float*)d_in[1];
  const float* V = (const float*)d_in[2];
  const float* pe = (const float*)d_in[3];
  const float* W = (const float*)d_in[4];
  const float* bias = (const float*)d_in[5];
  float* out = (float*)d_out;
  float* Y = (float*)d_ws;  // 128 MB scratch

  wtrans<<<16, 256, 0, stream>>>(W);
  yconv<<<2048, 256, 0, stream>>>(V, Y);
  attn_main<<<1024, 256, 0, stream>>>(Q, K, Y, pe, bias, out);
}

// Round 6
// 343.155 us; speedup vs baseline: 1.7792x; 1.0720x over previous
//
#include <hip/hip_runtime.h>
#include <math.h>

#define CH 64
#define S 64
#define S2 (64 * 64)
#define S3 (64 * 64 * 64)

__device__ float WT_buf[CH * CH];  // W transposed: WT[c][o]

// ---------------------------------------------------------------------------
// Kernel 0: transpose W (64x64) into WT_buf.
// ---------------------------------------------------------------------------
__global__ __launch_bounds__(256) void wtrans(const float* __restrict__ W) {
  int i = blockIdx.x * 256 + threadIdx.x;
  int o = i >> 6, c = i & 63;
  WT_buf[c * CH + o] = W[o * CH + c];
}

// ---------------------------------------------------------------------------
// Kernel 1: Y[b,o,q] = sum_c W[o,c] * V[b,c,q]. acc[64] (full ILP), contiguous
// scalar W rows from WT_buf.
// ---------------------------------------------------------------------------
__global__ __launch_bounds__(256) void yconv(const float* __restrict__ V,
                                             float* __restrict__ Y) {
  int idx = blockIdx.x * 256 + threadIdx.x;
  int b = idx >> 18;
  size_t base = ((size_t)b << 24) + (size_t)(idx & (S3 - 1));
  const float* vb = V + base;
  float acc[CH];
#pragma unroll
  for (int o = 0; o < CH; ++o) acc[o] = 0.f;
#pragma unroll 2
  for (int c = 0; c < CH; ++c) {
    float v = vb[(size_t)c << 18];
    const float* wr = WT_buf + c * CH;
#pragma unroll
    for (int o = 0; o < CH; ++o) acc[o] = fmaf(wr[o], v, acc[o]);
  }
  float* yb = Y + base;
#pragma unroll
  for (int o = 0; o < CH; ++o) yb[(size_t)o << 18] = acc[o];
}

// ---------------------------------------------------------------------------
// Kernel 2: barrier-free, LDS-free conv-attention. One wave per (b,d,h) row;
// lane = w. Per channel: 9 coalesced halo-row loads (clamped ptrs, OOB rows
// multiplied by 0), left/right w-taps via __shfl_up/__shfl_down(.,1) with the
// x-pad masked by a per-lane 0/1 factor. No LDS, no __syncthreads.
// Block = 4 waves covering h..h+3 (L1 reuse across dy). Grid 2048.
// ---------------------------------------------------------------------------
__global__ __launch_bounds__(256) void attn_main(const float* __restrict__ Q,
                                                 const float* __restrict__ K,
                                                 const float* __restrict__ Yv,
                                                 const float* __restrict__ pe,
                                                 const float* __restrict__ bias,
                                                 float* __restrict__ out) {
  int tid = threadIdx.x;
  int lane = tid & 63;
  int wv = tid >> 6;

  // XCD-aware bijective swizzle (2048 % 8 == 0)
  int raw = blockIdx.x;
  int sw = (raw & 7) * 256 + (raw >> 3);
  int b = sw >> 10;
  int r = sw & 1023;
  int d = r >> 4;                                             // 0..63
  int hu = __builtin_amdgcn_readfirstlane((r & 15) * 4 + wv);  // 0..63, uniform

  size_t bbase = (size_t)b << 24;
  const float* Qb = Q + bbase;
  const float* Kb = K + bbase;
  const float* Yb = Yv + bbase;
  float* outb = out + bbase;

  // per-lane x-pad masks for the shifted taps
  float lmL = (lane == 0) ? 0.f : 1.f;
  float lmR = (lane == 63) ? 0.f : 1.f;

  // uniform row bases (clamped) + OOB masks -> SGPRs
  const float* krow[9];
  const float* yrow[9];
  float okf[9];
#pragma unroll
  for (int dz = 0; dz < 3; ++dz)
#pragma unroll
    for (int dy = 0; dy < 3; ++dy) {
      int rr = dz * 3 + dy;
      int zz = d + dz - 1, yy = hu + dy - 1;
      bool ok = ((unsigned)zz < 64u) & ((unsigned)yy < 64u);
      int zc = zz < 0 ? 0 : (zz > 63 ? 63 : zz);
      int yc = yy < 0 ? 0 : (yy > 63 ? 63 : yy);
      krow[rr] = Kb + zc * S2 + yc * S;
      yrow[rr] = Yb + zc * S2 + yc * S;
      okf[rr] = ok ? 1.f : 0.f;
    }
  int pos = d * S2 + hu * S + lane;

  float s[27];
#pragma unroll
  for (int t = 0; t < 27; ++t) s[t] = 0.f;

  // ---- Phase A: scores ----
#pragma unroll 2
  for (int c = 0; c < CH; ++c) {
    int coff = c * S3;
    float q = Qb[coff + pos];
    float rv[9];
#pragma unroll
    for (int rr = 0; rr < 9; ++rr) rv[rr] = krow[rr][coff + lane];
#pragma unroll
    for (int rr = 0; rr < 9; ++rr) rv[rr] *= okf[rr];
    const float* pec = pe + c * 27;  // uniform -> scalar loads
#pragma unroll
    for (int rr = 0; rr < 9; ++rr) {
      float lft = __shfl_up(rv[rr], 1) * lmL;
      float rgt = __shfl_down(rv[rr], 1) * lmR;
      int t = rr * 3;
      s[t]     = fmaf(q, lft,    s[t]);
      s[t + 1] = fmaf(q, rv[rr], s[t + 1]);
      s[t + 2] = fmaf(q, rgt,    s[t + 2]);
    }
#pragma unroll
    for (int t = 0; t < 27; ++t) s[t] = fmaf(q, pec[t], s[t]);
  }

  // ---- softmax over 27 taps (base-2; normalization deferred) ----
  const float SC = 0.125f * 1.44269504088896f;
#pragma unroll
  for (int t = 0; t < 27; ++t) s[t] *= SC;
  float m = s[0];
#pragma unroll
  for (int t = 1; t < 27; ++t) m = fmaxf(m, s[t]);
  float sum = 0.f;
#pragma unroll
  for (int t = 0; t < 27; ++t) {
    s[t] = exp2f(s[t] - m);
    sum += s[t];
  }
  float inv = 1.f / sum;

  // ---- Phase B: gather Y with attention weights, write out ----
#pragma unroll 2
  for (int c = 0; c < CH; ++c) {
    int coff = c * S3;
    float rv[9];
#pragma unroll
    for (int rr = 0; rr < 9; ++rr) rv[rr] = yrow[rr][coff + lane];
#pragma unroll
    for (int rr = 0; rr < 9; ++rr) rv[rr] *= okf[rr];
    float o = 0.f;
#pragma unroll
    for (int rr = 0; rr < 9; ++rr) {
      float lft = __shfl_up(rv[rr], 1) * lmL;
      float rgt = __shfl_down(rv[rr], 1) * lmR;
      int t = rr * 3;
      o = fmaf(s[t], lft, o);
      o = fmaf(s[t + 1], rv[rr], o);
      o = fmaf(s[t + 2], rgt, o);
    }
    outb[coff + pos] = fmaf(o, inv, bias[c]);
  }
}

// ---------------------------------------------------------------------------
extern "C" void kernel_launch(void* const* d_in, const int* in_sizes, int n_in,
                              void* d_out, int out_size, void* d_ws, size_t ws_size,
                              hipStream_t stream) {
  const float* Q = (const float*)d_in[0];
  const float* K = (const float*)d_in[1];
  const float* V = (const float*)d_in[2];
  const float* pe = (const float*)d_in[3];
  const float* W = (const float*)d_in[4];
  const float* bias = (const float*)d_in[5];
  float* out = (float*)d_out;
  float* Y = (float*)d_ws;  // 128 MB scratch

  wtrans<<<16, 256, 0, stream>>>(W);
  yconv<<<2048, 256, 0, stream>>>(V, Y);
  attn_main<<<2048, 256, 0, stream>>>(Q, K, Y, pe, bias, out);
}

// Round 7
// 306.348 us; speedup vs baseline: 1.9930x; 1.1201x over previous
//
#include <hip/hip_runtime.h>
#include <math.h>

#define CH 64
#define S 64
#define S2 (64 * 64)
#define S3 (64 * 64 * 64)

__device__ float WT_buf[CH * CH];  // W transposed: WT[c][o]

// ---------------------------------------------------------------------------
// Kernel 0: transpose W (64x64) into WT_buf.
// ---------------------------------------------------------------------------
__global__ __launch_bounds__(256) void wtrans(const float* __restrict__ W) {
  int i = blockIdx.x * 256 + threadIdx.x;
  int o = i >> 6, c = i & 63;
  WT_buf[c * CH + o] = W[o * CH + c];
}

// ---------------------------------------------------------------------------
// Kernel 1: Y[b,o,q] = sum_c W[o,c] * V[b,c,q]. acc[64] (full ILP), contiguous
// scalar W rows from WT_buf. At its memory roofline (~85 us).
// ---------------------------------------------------------------------------
__global__ __launch_bounds__(256) void yconv(const float* __restrict__ V,
                                             float* __restrict__ Y) {
  int idx = blockIdx.x * 256 + threadIdx.x;
  int b = idx >> 18;
  size_t base = ((size_t)b << 24) + (size_t)(idx & (S3 - 1));
  const float* vb = V + base;
  float acc[CH];
#pragma unroll
  for (int o = 0; o < CH; ++o) acc[o] = 0.f;
#pragma unroll 2
  for (int c = 0; c < CH; ++c) {
    float v = vb[(size_t)c << 18];
    const float* wr = WT_buf + c * CH;
#pragma unroll
    for (int o = 0; o < CH; ++o) acc[o] = fmaf(wr[o], v, acc[o]);
  }
  float* yb = Y + base;
#pragma unroll
  for (int o = 0; o < CH; ++o) yb[(size_t)o << 18] = acc[o];
}

// ---------------------------------------------------------------------------
// Kernel 2: barrier-free, LDS-free conv-attention; cross-lane taps hoisted
// OUT of the channel loop. One wave per (b,d,h) row; lane = w.
// Phase A per channel: 9 row loads + q load, 2 q-shuffles, 27+27 FMA into
// lane-local accumulators (sC/sXR/sXL + pe-part). 18 assembly shuffles once.
// Phase B: weights pre-shuffled once (18), per channel 27 FMA + 2 shuffles.
// DS ops/wave: ~296 vs 2304 in the per-channel-shuffle version.
// ---------------------------------------------------------------------------
__global__ __launch_bounds__(256) void attn_main(const float* __restrict__ Q,
                                                 const float* __restrict__ K,
                                                 const float* __restrict__ Yv,
                                                 const float* __restrict__ pe,
                                                 const float* __restrict__ bias,
                                                 float* __restrict__ out) {
  int tid = threadIdx.x;
  int lane = tid & 63;
  int wv = tid >> 6;

  // XCD-aware bijective swizzle (2048 % 8 == 0)
  int raw = blockIdx.x;
  int sw = (raw & 7) * 256 + (raw >> 3);
  int b = sw >> 10;
  int r = sw & 1023;
  int d = r >> 4;                                             // 0..63
  int hu = __builtin_amdgcn_readfirstlane((r & 15) * 4 + wv);  // 0..63, uniform

  size_t bbase = (size_t)b << 24;
  const float* Qb = Q + bbase;
  const float* Kb = K + bbase;
  const float* Yb = Yv + bbase;
  float* outb = out + bbase;

  // per-lane x-pad masks for received shuffles
  float lmL = (lane == 0) ? 0.f : 1.f;
  float lmR = (lane == 63) ? 0.f : 1.f;

  // uniform row bases (clamped) + OOB masks (kept scalar)
  const float* krow[9];
  const float* yrow[9];
  float okf[9];
#pragma unroll
  for (int dz = 0; dz < 3; ++dz)
#pragma unroll
    for (int dy = 0; dy < 3; ++dy) {
      int rr = dz * 3 + dy;
      int zz = d + dz - 1, yy = hu + dy - 1;
      bool ok = ((unsigned)zz < 64u) & ((unsigned)yy < 64u);
      int zc = zz < 0 ? 0 : (zz > 63 ? 63 : zz);
      int yc = yy < 0 ? 0 : (yy > 63 ? 63 : yy);
      krow[rr] = Kb + zc * S2 + yc * S;
      yrow[rr] = Yb + zc * S2 + yc * S;
      okf[rr] = ok ? 1.f : 0.f;
    }
  int pos = d * S2 + hu * S + lane;

  float spe[27];  // pe part (always at own lane, unmasked)
  float sC[9], sXR[9], sXL[9];
#pragma unroll
  for (int t = 0; t < 27; ++t) spe[t] = 0.f;
#pragma unroll
  for (int rr = 0; rr < 9; ++rr) { sC[rr] = 0.f; sXR[rr] = 0.f; sXL[rr] = 0.f; }

  // ---- Phase A: scores (no per-channel tap shuffles) ----
#pragma unroll 2
  for (int c = 0; c < CH; ++c) {
    int coff = c * S3;
    float q = Qb[coff + pos];
    float rv[9];
#pragma unroll
    for (int rr = 0; rr < 9; ++rr) rv[rr] = krow[rr][coff + lane];
    float qR = __shfl_down(q, 1);  // q of lane+1
    float qL = __shfl_up(q, 1);    // q of lane-1
#pragma unroll
    for (int rr = 0; rr < 9; ++rr) {
      sC[rr]  = fmaf(q,  rv[rr], sC[rr]);
      sXR[rr] = fmaf(qR, rv[rr], sXR[rr]);  // belongs to lane+1's left tap
      sXL[rr] = fmaf(qL, rv[rr], sXL[rr]);  // belongs to lane-1's right tap
    }
    const float* pec = pe + c * 27;  // uniform -> scalar loads
#pragma unroll
    for (int t = 0; t < 27; ++t) spe[t] = fmaf(q, pec[t], spe[t]);
  }

  // ---- assemble the 27 tap scores (18 shuffles, once) ----
  float s[27];
#pragma unroll
  for (int rr = 0; rr < 9; ++rr) {
    float lt = __shfl_up(sXR[rr], 1);    // = sum_c q[w]*K[rr][w-1]
    float rt = __shfl_down(sXL[rr], 1);  // = sum_c q[w]*K[rr][w+1]
    s[rr * 3]     = fmaf(lt * lmL, okf[rr], spe[rr * 3]);
    s[rr * 3 + 1] = fmaf(sC[rr],   okf[rr], spe[rr * 3 + 1]);
    s[rr * 3 + 2] = fmaf(rt * lmR, okf[rr], spe[rr * 3 + 2]);
  }

  // ---- softmax over 27 taps (base-2; normalization folded into weights) ----
  const float SC = 0.125f * 1.44269504088896f;
#pragma unroll
  for (int t = 0; t < 27; ++t) s[t] *= SC;
  float m = s[0];
#pragma unroll
  for (int t = 1; t < 27; ++t) m = fmaxf(m, s[t]);
  float sum = 0.f;
#pragma unroll
  for (int t = 0; t < 27; ++t) {
    s[t] = exp2f(s[t] - m);
    sum += s[t];
  }
  float inv = 1.f / sum;

  // ---- Phase B weights: fold inv + row mask; pre-shuffle cross weights ----
  float w3[27];
#pragma unroll
  for (int rr = 0; rr < 9; ++rr) {
    float f = inv * okf[rr];  // OOB rows: V-pad = 0 -> weight 0
    w3[rr * 3]     = s[rr * 3] * f;
    w3[rr * 3 + 1] = s[rr * 3 + 1] * f;
    w3[rr * 3 + 2] = s[rr * 3 + 2] * f;
  }
  float sLs[9], sRs[9];
#pragma unroll
  for (int rr = 0; rr < 9; ++rr) {
    sLs[rr] = __shfl_down(w3[rr * 3], 1);      // left-tap weight of lane+1
    sRs[rr] = __shfl_up(w3[rr * 3 + 2], 1);    // right-tap weight of lane-1
  }

  // ---- Phase B: gather Y, write out (2 shuffles per channel) ----
#pragma unroll 2
  for (int c = 0; c < CH; ++c) {
    int coff = c * S3;
    float rv[9];
#pragma unroll
    for (int rr = 0; rr < 9; ++rr) rv[rr] = yrow[rr][coff + lane];
    float own = 0.f, cR = 0.f, cL = 0.f;
#pragma unroll
    for (int rr = 0; rr < 9; ++rr) {
      own = fmaf(w3[rr * 3 + 1], rv[rr], own);
      cR  = fmaf(sLs[rr], rv[rr], cR);  // contribution to out[w+1]
      cL  = fmaf(sRs[rr], rv[rr], cL);  // contribution to out[w-1]
    }
    float val = own + __shfl_up(cR, 1) * lmL + __shfl_down(cL, 1) * lmR;
    outb[coff + pos] = val + bias[c];
  }
}

// ---------------------------------------------------------------------------
extern "C" void kernel_launch(void* const* d_in, const int* in_sizes, int n_in,
                              void* d_out, int out_size, void* d_ws, size_t ws_size,
                              hipStream_t stream) {
  const float* Q = (const float*)d_in[0];
  const float* K = (const float*)d_in[1];
  const float* V = (const float*)d_in[2];
  const float* pe = (const float*)d_in[3];
  const float* W = (const float*)d_in[4];
  const float* bias = (const float*)d_in[5];
  float* out = (float*)d_out;
  float* Y = (float*)d_ws;  // 128 MB scratch

  wtrans<<<16, 256, 0, stream>>>(W);
  yconv<<<2048, 256, 0, stream>>>(V, Y);
  attn_main<<<2048, 256, 0, stream>>>(Q, K, Y, pe, bias, out);
}

// Round 8
// 300.609 us; speedup vs baseline: 2.0310x; 1.0191x over previous
//
#include <hip/hip_runtime.h>
#include <math.h>

#define CH 64
#define S 64
#define S2 (64 * 64)
#define S3 (64 * 64 * 64)

__device__ float WT_buf[CH * CH];  // W transposed: WT[c][o]

// ---------------------------------------------------------------------------
// Kernel 0: transpose W (64x64) into WT_buf (columns of W become contiguous
// rows -> wide scalar loads in the fused kernel's W-accumulation).
// ---------------------------------------------------------------------------
__global__ __launch_bounds__(256) void wtrans(const float* __restrict__ W) {
  int i = blockIdx.x * 256 + threadIdx.x;
  int o = i >> 6, c = i & 63;
  WT_buf[c * CH + o] = W[o * CH + c];
}

// ---------------------------------------------------------------------------
// Fused kernel: scores -> softmax -> V-gather -> W-projection -> out, in one
// pass. Barrier-free, LDS-free. One wave per (b,d,h) row; lane = w.
//
// Phase A (per channel): 9 K-row loads + q; cross-lane tap terms accumulated
// at the producing lane with shuffled q (2 shuffles/channel); pe part in
// spe[27]. 18 assembly shuffles once at the end.
// Phase B (per channel): 9 V-row loads; 27 gather FMAs -> scalar x_c; then
// acc_o[o] += WT[c][o] * x_c (64 statically-indexed FMAs -> no scratch).
// This replaces the former yconv kernel (saves 268 MB HBM round-trip).
// Epilogue: out[o] = acc_o[o] + bias[o], 64 coalesced row stores.
// ---------------------------------------------------------------------------
__global__ __launch_bounds__(256) void attn_fused(const float* __restrict__ Q,
                                                  const float* __restrict__ K,
                                                  const float* __restrict__ V,
                                                  const float* __restrict__ pe,
                                                  const float* __restrict__ bias,
                                                  float* __restrict__ out) {
  int tid = threadIdx.x;
  int lane = tid & 63;
  int wv = tid >> 6;

  // XCD-aware bijective swizzle (2048 % 8 == 0)
  int raw = blockIdx.x;
  int sw = (raw & 7) * 256 + (raw >> 3);
  int b = sw >> 10;
  int r = sw & 1023;
  int d = r >> 4;                                             // 0..63
  int hu = __builtin_amdgcn_readfirstlane((r & 15) * 4 + wv);  // 0..63, uniform

  size_t bbase = (size_t)b << 24;
  const float* Qb = Q + bbase;
  const float* Kb = K + bbase;
  const float* Vb = V + bbase;
  float* outb = out + bbase;

  // per-lane x-pad masks for received shuffles
  float lmL = (lane == 0) ? 0.f : 1.f;
  float lmR = (lane == 63) ? 0.f : 1.f;

  // uniform row bases (clamped) + OOB masks
  const float* krow[9];
  const float* vrow[9];
  float okf[9];
#pragma unroll
  for (int dz = 0; dz < 3; ++dz)
#pragma unroll
    for (int dy = 0; dy < 3; ++dy) {
      int rr = dz * 3 + dy;
      int zz = d + dz - 1, yy = hu + dy - 1;
      bool ok = ((unsigned)zz < 64u) & ((unsigned)yy < 64u);
      int zc = zz < 0 ? 0 : (zz > 63 ? 63 : zz);
      int yc = yy < 0 ? 0 : (yy > 63 ? 63 : yy);
      krow[rr] = Kb + zc * S2 + yc * S;
      vrow[rr] = Vb + zc * S2 + yc * S;
      okf[rr] = ok ? 1.f : 0.f;
    }
  int pos = d * S2 + hu * S + lane;

  float spe[27];  // pe part (always at own lane, unmasked)
  float sC[9], sXR[9], sXL[9];
#pragma unroll
  for (int t = 0; t < 27; ++t) spe[t] = 0.f;
#pragma unroll
  for (int rr = 0; rr < 9; ++rr) { sC[rr] = 0.f; sXR[rr] = 0.f; sXL[rr] = 0.f; }

  // ---- Phase A: scores (2 shuffles per channel, deep load pipelining) ----
#pragma unroll 4
  for (int c = 0; c < CH; ++c) {
    int coff = c * S3;
    float q = Qb[coff + pos];
    float rv[9];
#pragma unroll
    for (int rr = 0; rr < 9; ++rr) rv[rr] = krow[rr][coff + lane];
    float qR = __shfl_down(q, 1);  // q of lane+1
    float qL = __shfl_up(q, 1);    // q of lane-1
#pragma unroll
    for (int rr = 0; rr < 9; ++rr) {
      sC[rr]  = fmaf(q,  rv[rr], sC[rr]);
      sXR[rr] = fmaf(qR, rv[rr], sXR[rr]);  // belongs to lane+1's left tap
      sXL[rr] = fmaf(qL, rv[rr], sXL[rr]);  // belongs to lane-1's right tap
    }
    const float* pec = pe + c * 27;  // uniform -> scalar loads
#pragma unroll
    for (int t = 0; t < 27; ++t) spe[t] = fmaf(q, pec[t], spe[t]);
  }

  // ---- assemble the 27 tap scores (18 shuffles, once) ----
  float s[27];
#pragma unroll
  for (int rr = 0; rr < 9; ++rr) {
    float lt = __shfl_up(sXR[rr], 1);    // = sum_c q[w]*K[rr][w-1]
    float rt = __shfl_down(sXL[rr], 1);  // = sum_c q[w]*K[rr][w+1]
    s[rr * 3]     = fmaf(lt * lmL, okf[rr], spe[rr * 3]);
    s[rr * 3 + 1] = fmaf(sC[rr],   okf[rr], spe[rr * 3 + 1]);
    s[rr * 3 + 2] = fmaf(rt * lmR, okf[rr], spe[rr * 3 + 2]);
  }

  // ---- softmax over 27 taps (base-2; normalization folded into weights) ----
  const float SC = 0.125f * 1.44269504088896f;
#pragma unroll
  for (int t = 0; t < 27; ++t) s[t] *= SC;
  float m = s[0];
#pragma unroll
  for (int t = 1; t < 27; ++t) m = fmaxf(m, s[t]);
  float sum = 0.f;
#pragma unroll
  for (int t = 0; t < 27; ++t) {
    s[t] = exp2f(s[t] - m);
    sum += s[t];
  }
  float inv = 1.f / sum;

  // ---- weights: fold inv + row mask; pre-shuffle cross weights; keep only
  //      wC / sLs / sRs live through phase B (27 regs) ----
  float wC[9], sLs[9], sRs[9];
#pragma unroll
  for (int rr = 0; rr < 9; ++rr) {
    float f = inv * okf[rr];  // OOB rows: V-pad = 0 -> weight 0
    float wL = s[rr * 3] * f;
    wC[rr]   = s[rr * 3 + 1] * f;
    float wR = s[rr * 3 + 2] * f;
    sLs[rr] = __shfl_down(wL, 1);  // left-tap weight of lane+1
    sRs[rr] = __shfl_up(wR, 1);    // right-tap weight of lane-1
  }

  // ---- Phase B: gather V + progressive W-projection ----
  float acc_o[CH];
#pragma unroll
  for (int o = 0; o < CH; ++o) acc_o[o] = 0.f;

#pragma unroll 2
  for (int c = 0; c < CH; ++c) {
    int coff = c * S3;
    float rv[9];
#pragma unroll
    for (int rr = 0; rr < 9; ++rr) rv[rr] = vrow[rr][coff + lane];
    float own = 0.f, cR = 0.f, cL = 0.f;
#pragma unroll
    for (int rr = 0; rr < 9; ++rr) {
      own = fmaf(wC[rr], rv[rr], own);
      cR  = fmaf(sLs[rr], rv[rr], cR);  // contribution to x of lane+1
      cL  = fmaf(sRs[rr], rv[rr], cL);  // contribution to x of lane-1
    }
    float x_c = own + __shfl_up(cR, 1) * lmL + __shfl_down(cL, 1) * lmR;
    const float* wr = WT_buf + c * CH;  // uniform, contiguous -> s_load_dwordx16
#pragma unroll
    for (int o = 0; o < CH; ++o) acc_o[o] = fmaf(wr[o], x_c, acc_o[o]);
  }

  // ---- epilogue: bias + 64 coalesced row stores ----
#pragma unroll 4
  for (int o = 0; o < CH; ++o) outb[o * S3 + pos] = acc_o[o] + bias[o];
}

// ---------------------------------------------------------------------------
extern "C" void kernel_launch(void* const* d_in, const int* in_sizes, int n_in,
                              void* d_out, int out_size, void* d_ws, size_t ws_size,
                              hipStream_t stream) {
  const float* Q = (const float*)d_in[0];
  const float* K = (const float*)d_in[1];
  const float* V = (const float*)d_in[2];
  const float* pe = (const float*)d_in[3];
  const float* W = (const float*)d_in[4];
  const float* bias = (const float*)d_in[5];
  float* out = (float*)d_out;

  wtrans<<<16, 256, 0, stream>>>(W);
  attn_fused<<<2048, 256, 0, stream>>>(Q, K, V, pe, bias, out);
}